// Round 1
// 184.619 us; speedup vs baseline: 1.0617x; 1.0617x over previous
//
#include <hip/hip_runtime.h>

// Conv2d 3x3 pad1 stride1, x[1,256,224,224] f32, w[256,256,3,3] f32 -> out[256,224,224] f32
// Implicit GEMM: M=256 (co), N=50176 (h*224+w), K=2304 (tap-major: k = (dh*3+dw)*256 + ci)
// R7: occupancy attack. Back to m97 geometry: 128x128 block, 4 waves (256 thr), wave-tile
//     64x64 -> 8 ds_read_b128 : 16 MFMA per K-step per wave (2:1, same as m97's 874-912 TF
//     structure). BK=32 dbuf, one barrier/iter, __launch_bounds__(256,3) -> 12 waves/CU
//     (vs R6's 6). Staging per thread halves to 4 global_load_lds per K-step.

#define H 224
#define W 224
#define NPOS (H*W)          // 50176
#define CI 256
#define CO 256
#define KDIM 2304
#define HP 226              // padded
#define XP_ELEMS (HP*HP*CI) // 13,075,456 shorts
#define AP_ELEMS (CO*KDIM)  // 589,824 shorts

typedef __bf16 bf16x8 __attribute__((ext_vector_type(8)));
typedef float f32x4 __attribute__((ext_vector_type(4)));

__device__ __forceinline__ unsigned short f2bf(float f) {
    unsigned int u = __float_as_uint(f);
    u += 0x7fff + ((u >> 16) & 1);   // round-to-nearest-even
    return (unsigned short)(u >> 16);
}

__device__ __forceinline__ void load_lds16(const unsigned short* g, unsigned short* l) {
    __builtin_amdgcn_global_load_lds(
        (const __attribute__((address_space(1))) void*)g,
        (__attribute__((address_space(3))) void*)l,
        16, 0, 0);
}

// ---- fused: weight f32 [co][ci][3][3] -> bf16 A'[co][tap*256+ci]  (blocks 0..2303)
//      + zero the 1-px border of Xp [226][226][256]                 (blocks 2304..3203)
__global__ void prologue_kernel(const float* __restrict__ w, unsigned short* __restrict__ ap,
                                unsigned short* __restrict__ xp) {
    if (blockIdx.x < AP_ELEMS / 256) {
        int o = blockIdx.x * 256 + threadIdx.x;  // o = co*2304 + tap*256 + ci
        int co = o / KDIM;
        int rem = o - co * KDIM;
        int tap = rem >> 8;
        int ci = rem & 255;
        ap[o] = f2bf(w[(co * CI + ci) * 9 + tap]);
    } else {
        int idx = (blockIdx.x - AP_ELEMS / 256) * 256 + threadIdx.x;  // 230400 total
        int hp, wp, ci;
        if (idx < 2 * HP * CI) {                 // rows 0 and 225
            int r = idx / (HP * CI);
            int rem = idx - r * (HP * CI);
            hp = r * (HP - 1);
            wp = rem / CI;
            ci = rem & (CI - 1);
        } else {
            int i2 = idx - 2 * HP * CI;          // cols 0 and 225, h=1..224
            int side = i2 / (H * CI);
            int rem = i2 - side * (H * CI);
            hp = 1 + rem / CI;
            wp = side * (HP - 1);
            ci = rem & (CI - 1);
        }
        xp[(hp * HP + wp) * CI + ci] = 0;
    }
}

// ---- input: f32 [ci][224][224] -> bf16 padded NHWC Xp[226][226][256] interior ----
// LDS-tiled transpose: 64 ci x 64 p per block; both global phases coalesced.
__global__ void xtrans_kernel(const float* __restrict__ x, unsigned short* __restrict__ xp) {
    __shared__ unsigned short tile[64][66];
    const unsigned int pBase = blockIdx.x * 64;
    const unsigned int ciBase = blockIdx.y * 64;
    const unsigned int t = threadIdx.x;
    {
        const unsigned int p_l = t & 63;
        const unsigned int c0 = t >> 6;          // 0..3
#pragma unroll
        for (int i = 0; i < 16; ++i) {
            const unsigned int ci_l = c0 + i * 4;
            tile[ci_l][p_l] = f2bf(x[(ciBase + ci_l) * NPOS + pBase + p_l]);
        }
    }
    __syncthreads();
    {
        const unsigned int ci_l = t & 63;
        const unsigned int p0 = t >> 6;          // 0..3
#pragma unroll
        for (int i = 0; i < 16; ++i) {
            const unsigned int p_l = p0 + i * 4;
            const unsigned int p = pBase + p_l;
            const unsigned int hi = p / W;
            const unsigned int wi = p - hi * W;
            xp[((hi + 1) * HP + (wi + 1)) * CI + ciBase + ci_l] = tile[ci_l][p_l];
        }
    }
}

// ---- implicit GEMM: 128x128 block, 4 waves (2Mx2N), wave-tile 64x64, BK=32, dbuf ----
// Per K-step per wave: 4 A-frags + 4 B-frags (8 ds_read_b128) -> 16 MFMA 16x16x32.
// Swizzle (4 chunks of 8 shorts per 32-short row):
//   store: lane l -> row += (l>>2), slot l&3, source chunk (l&3)^((l>>2)&3)
//   read : chunk quad of row r lives at slot quad^(r&3); r&3 == ln15&3
__global__ __launch_bounds__(256, 3) void gemm_conv_kernel(
    const unsigned short* __restrict__ Ap,   // [256][2304] bf16
    const unsigned short* __restrict__ Xp,   // [226][226][256] bf16
    float* __restrict__ out)                 // [256][50176]
{
    __shared__ unsigned short Als[2][4096];  // 128 rows x 32
    __shared__ unsigned short Bls[2][4096];  // 128 rows x 32

    const int tid = threadIdx.x;
    const int Nb = blockIdx.x;               // 0..391
    const int Mb = blockIdx.y;               // 0..1
    const int wave = tid >> 6;               // 0..3
    const int wm = wave >> 1;                // 0..1 (M half)
    const int wn = wave & 1;                 // 0..1 (N half)
    const int lane = tid & 63;
    const int ln15 = lane & 15;
    const int quad = lane >> 4;
    const int sw = ln15 & 3;

    // ---- staging source pointers (each thread stages 2 A-chunks + 2 B-chunks) ----
    const int l2 = lane >> 2;                // 0..15
    const int c4 = (lane & 3) ^ (l2 & 3);    // swizzled source chunk

    const unsigned short* a_src[2];
    const unsigned short* b_src[2];
#pragma unroll
    for (int j = 0; j < 2; ++j) {
        const int row = (wave * 2 + j) * 16 + l2;          // 0..127
        a_src[j] = Ap + (Mb * 128 + row) * KDIM + c4 * 8;  // + kc*32
        unsigned int p = Nb * 128 + row;
        unsigned int hi = p / W, wi = p - hi * W;
        b_src[j] = Xp + (hi * HP + wi) * CI + c4 * 8;      // + tap/ci offset
    }

    f32x4 acc[4][4];
#pragma unroll
    for (int mi = 0; mi < 4; ++mi)
#pragma unroll
        for (int ni = 0; ni < 4; ++ni)
            acc[mi][ni] = (f32x4){0.f, 0.f, 0.f, 0.f};

    // stage tile kc into buffer buf (wave-uniform LDS base; lane*16B implicit)
    auto stage = [&](int kc, int buf) {
        const int tap = kc >> 3;             // 0..8
        const int dh = tap / 3, dw = tap - dh * 3;
        const int boff = (dh * HP + dw) * CI + (kc & 7) * 32;
        const int aoff = kc * 32;
#pragma unroll
        for (int j = 0; j < 2; ++j) {
            load_lds16(a_src[j] + aoff, &Als[buf][(wave * 2 + j) * 512]);
            load_lds16(b_src[j] + boff, &Bls[buf][(wave * 2 + j) * 512]);
        }
    };

    stage(0, 0);
    __syncthreads();                         // drain vmcnt: buffer 0 ready

    for (int kc = 0; kc < 72; ++kc) {
        const int cur = kc & 1;
        if (kc < 71) stage(kc + 1, cur ^ 1); // async into the OTHER buffer

        bf16x8 af[4], bfr[4];
#pragma unroll
        for (int mi = 0; mi < 4; ++mi)
            af[mi] = *(const bf16x8*)&Als[cur][(wm * 64 + mi * 16 + ln15) * 32 +
                                              ((quad ^ sw) * 8)];
#pragma unroll
        for (int ni = 0; ni < 4; ++ni)
            bfr[ni] = *(const bf16x8*)&Bls[cur][(wn * 64 + ni * 16 + ln15) * 32 +
                                               ((quad ^ sw) * 8)];
#pragma unroll
        for (int mi = 0; mi < 4; ++mi)
#pragma unroll
            for (int ni = 0; ni < 4; ++ni)
                acc[mi][ni] = __builtin_amdgcn_mfma_f32_16x16x32_bf16(
                    af[mi], bfr[ni], acc[mi][ni], 0, 0, 0);

        __syncthreads();                     // joins: reads of cur done, next buffer landed
    }

    // epilogue: C/D layout col = lane&15 (n=p), row = quad*4 + reg (m=co)
    const int pcol = Nb * 128 + wn * 64 + ln15;
    const int corow = Mb * 128 + wm * 64 + quad * 4;
#pragma unroll
    for (int mi = 0; mi < 4; ++mi)
#pragma unroll
        for (int ni = 0; ni < 4; ++ni)
#pragma unroll
            for (int r = 0; r < 4; ++r)
                out[(corow + mi * 16 + r) * NPOS + pcol + ni * 16] = acc[mi][ni][r];
}

extern "C" void kernel_launch(void* const* d_in, const int* in_sizes, int n_in,
                              void* d_out, int out_size, void* d_ws, size_t ws_size,
                              hipStream_t stream) {
    const float* x = (const float*)d_in[0];       // [1,256,224,224]
    const float* w = (const float*)d_in[1];       // [256,256,3,3]
    float* out = (float*)d_out;                   // [256,224,224]

    unsigned short* xp = (unsigned short*)d_ws;        // 13,075,456 shorts
    unsigned short* ap = xp + XP_ELEMS;                // 589,824 shorts

    prologue_kernel<<<AP_ELEMS / 256 + 900, 256, 0, stream>>>(w, ap, xp);
    xtrans_kernel<<<dim3(NPOS / 64, CI / 64), 256, 0, stream>>>(x, xp);
    gemm_conv_kernel<<<dim3(NPOS / 128, CO / 128), 256, 0, stream>>>(ap, xp, out);
}

// Round 2
// 180.643 us; speedup vs baseline: 1.0851x; 1.0220x over previous
//
#include <hip/hip_runtime.h>

// Conv2d 3x3 pad1 stride1, x[1,256,224,224] f32, w[256,256,3,3] f32 -> out[256,224,224] f32
// Implicit GEMM: M=256 (co), N=50176 (h*224+w), K=2304 (tap-major: k = (dh*3+dw)*256 + ci)
// R8: prep attack. Rounds 0-1 show total-gemm ~= 90us constant: the scalar-load xtrans +
//     stride-9 prologue dominate. Fuse them into ONE prep_kernel, fully vectorized:
//     float4 reads / ushort8 writes (G13), per-co LDS weight transpose, ushort8 border zero.
//     gemm_conv_kernel is byte-identical to R7 (93us, isolates the A/B).

#define H 224
#define W 224
#define NPOS (H*W)          // 50176
#define CI 256
#define CO 256
#define KDIM 2304
#define HP 226              // padded
#define XP_ELEMS (HP*HP*CI) // 13,075,456 shorts
#define AP_ELEMS (CO*KDIM)  // 589,824 shorts

typedef __bf16 bf16x8 __attribute__((ext_vector_type(8)));
typedef float f32x4 __attribute__((ext_vector_type(4)));
typedef unsigned short u16x4 __attribute__((ext_vector_type(4)));
typedef unsigned short u16x8 __attribute__((ext_vector_type(8)));
typedef float f32x4v __attribute__((ext_vector_type(4)));

__device__ __forceinline__ unsigned short f2bf(float f) {
    unsigned int u = __float_as_uint(f);
    u += 0x7fff + ((u >> 16) & 1);   // round-to-nearest-even
    return (unsigned short)(u >> 16);
}

__device__ __forceinline__ void load_lds16(const unsigned short* g, unsigned short* l) {
    __builtin_amdgcn_global_load_lds(
        (const __attribute__((address_space(1))) void*)g,
        (__attribute__((address_space(3))) void*)l,
        16, 0, 0);
}

// ---- fused prep: xtrans (blocks 0..3135) + weight transform (3136..3391)
//      + Xp border zero (3392..3504). One launch, all regions disjoint writes.
// xtrans: f32 [ci][224][224] -> bf16 padded NHWC Xp[226][226][256] interior.
//   64p x 64ci tile/block. Phase1: float4 reads along p (16B/lane), bf16 convert,
//   ds_write_b64 into [64][68]-padded tile. Phase2: gather 8 ci per thread (scalar
//   u16 LDS reads, ~4-way), ushort8 16B coalesced global writes along ci.
// weights: one co per block. Coalesced f32 reads of w[co][*], bf16 to LDS in source
//   order, then coalesced writes ap[co*2304 + tap*256 + ci] from LDS transpose.
// border: 28,800 ushort8 zero-stores (rows 0/225 full; cols 0/225 h=1..224).
#define XT_BLOCKS 3136      // 784 * 4
#define WT_BLOCKS 256
#define BORDER_V8 28800     // 230,400 shorts / 8
#define ROW_V8 7232         // 226*256/8
__global__ void prep_kernel(const float* __restrict__ x, const float* __restrict__ w,
                            unsigned short* __restrict__ ap, unsigned short* __restrict__ xp) {
    __shared__ unsigned short smem[64 * 68];   // 8704B; weight region uses first 2304
    const int bx = blockIdx.x;
    const int t = threadIdx.x;

    if (bx < XT_BLOCKS) {
        // ---------------- xtrans ----------------
        const unsigned int pBase = (unsigned int)(bx % 784) * 64;
        const unsigned int ciBase = (unsigned int)(bx / 784) * 64;
        {
            const int p4 = (t & 15) * 4;
            const int c0 = t >> 4;               // 0..15
#pragma unroll
            for (int i = 0; i < 4; ++i) {
                const int ci_l = c0 + i * 16;
                const f32x4 v = *(const f32x4*)&x[(ciBase + ci_l) * NPOS + pBase + p4];
                u16x4 s;
                s[0] = f2bf(v[0]); s[1] = f2bf(v[1]); s[2] = f2bf(v[2]); s[3] = f2bf(v[3]);
                *(u16x4*)&smem[ci_l * 68 + p4] = s;
            }
        }
        __syncthreads();
        {
            const int ci0 = (t & 7) * 8;
            const int pr = t >> 3;               // 0..31
#pragma unroll
            for (int j = 0; j < 2; ++j) {
                const int p_l = pr + j * 32;
                const unsigned int p = pBase + p_l;
                const unsigned int hi = p / W, wi = p - hi * W;
                u16x8 v;
#pragma unroll
                for (int k = 0; k < 8; ++k) v[k] = smem[(ci0 + k) * 68 + p_l];
                *(u16x8*)&xp[((hi + 1) * HP + (wi + 1)) * CI + ciBase + ci0] = v;
            }
        }
    } else if (bx < XT_BLOCKS + WT_BLOCKS) {
        // ---------------- weight f32 [co][ci][3][3] -> bf16 A'[co][tap*256+ci] ----------------
        const int co = bx - XT_BLOCKS;
        const float* wc = w + co * KDIM;
#pragma unroll
        for (int i = 0; i < 9; ++i)
            smem[i * 256 + t] = f2bf(wc[i * 256 + t]);   // smem[ci*9+tap] = bf16(w[co][ci][tap])
        __syncthreads();
        unsigned short* apc = ap + co * KDIM;
#pragma unroll
        for (int tap = 0; tap < 9; ++tap)
            apc[tap * 256 + t] = smem[t * 9 + tap];      // coalesced 2B writes (128B/wave)
    } else {
        // ---------------- Xp border zero, ushort8 ----------------
        const int idx = (bx - XT_BLOCKS - WT_BLOCKS) * 256 + t;
        if (idx < BORDER_V8) {
            unsigned short* p;
            if (idx < 2 * ROW_V8) {              // rows 0 and 225, full width
                const int r = idx / ROW_V8;
                const int off = idx - r * ROW_V8;
                p = xp + r * (225 * HP * CI) + off * 8;
            } else {
                const int i2 = idx - 2 * ROW_V8;
                const int seg = i2 >> 5;         // 0..447
                const int o = i2 & 31;
                const int hp = 1 + (seg >> 1);
                const int wp = (seg & 1) * 225;
                p = xp + (hp * HP + wp) * CI + o * 8;
            }
            *(u16x8*)p = (u16x8){0, 0, 0, 0, 0, 0, 0, 0};
        }
    }
}

// ---- implicit GEMM: 128x128 block, 4 waves (2Mx2N), wave-tile 64x64, BK=32, dbuf ----
// (byte-identical to R7: 93us, MfmaUtil ~26)
__global__ __launch_bounds__(256, 3) void gemm_conv_kernel(
    const unsigned short* __restrict__ Ap,   // [256][2304] bf16
    const unsigned short* __restrict__ Xp,   // [226][226][256] bf16
    float* __restrict__ out)                 // [256][50176]
{
    __shared__ unsigned short Als[2][4096];  // 128 rows x 32
    __shared__ unsigned short Bls[2][4096];  // 128 rows x 32

    const int tid = threadIdx.x;
    const int Nb = blockIdx.x;               // 0..391
    const int Mb = blockIdx.y;               // 0..1
    const int wave = tid >> 6;               // 0..3
    const int wm = wave >> 1;                // 0..1 (M half)
    const int wn = wave & 1;                 // 0..1 (N half)
    const int lane = tid & 63;
    const int ln15 = lane & 15;
    const int quad = lane >> 4;
    const int sw = ln15 & 3;

    const int l2 = lane >> 2;                // 0..15
    const int c4 = (lane & 3) ^ (l2 & 3);    // swizzled source chunk

    const unsigned short* a_src[2];
    const unsigned short* b_src[2];
#pragma unroll
    for (int j = 0; j < 2; ++j) {
        const int row = (wave * 2 + j) * 16 + l2;          // 0..127
        a_src[j] = Ap + (Mb * 128 + row) * KDIM + c4 * 8;  // + kc*32
        unsigned int p = Nb * 128 + row;
        unsigned int hi = p / W, wi = p - hi * W;
        b_src[j] = Xp + (hi * HP + wi) * CI + c4 * 8;      // + tap/ci offset
    }

    f32x4 acc[4][4];
#pragma unroll
    for (int mi = 0; mi < 4; ++mi)
#pragma unroll
        for (int ni = 0; ni < 4; ++ni)
            acc[mi][ni] = (f32x4){0.f, 0.f, 0.f, 0.f};

    auto stage = [&](int kc, int buf) {
        const int tap = kc >> 3;             // 0..8
        const int dh = tap / 3, dw = tap - dh * 3;
        const int boff = (dh * HP + dw) * CI + (kc & 7) * 32;
        const int aoff = kc * 32;
#pragma unroll
        for (int j = 0; j < 2; ++j) {
            load_lds16(a_src[j] + aoff, &Als[buf][(wave * 2 + j) * 512]);
            load_lds16(b_src[j] + boff, &Bls[buf][(wave * 2 + j) * 512]);
        }
    };

    stage(0, 0);
    __syncthreads();                         // drain vmcnt: buffer 0 ready

    for (int kc = 0; kc < 72; ++kc) {
        const int cur = kc & 1;
        if (kc < 71) stage(kc + 1, cur ^ 1); // async into the OTHER buffer

        bf16x8 af[4], bfr[4];
#pragma unroll
        for (int mi = 0; mi < 4; ++mi)
            af[mi] = *(const bf16x8*)&Als[cur][(wm * 64 + mi * 16 + ln15) * 32 +
                                              ((quad ^ sw) * 8)];
#pragma unroll
        for (int ni = 0; ni < 4; ++ni)
            bfr[ni] = *(const bf16x8*)&Bls[cur][(wn * 64 + ni * 16 + ln15) * 32 +
                                               ((quad ^ sw) * 8)];
#pragma unroll
        for (int mi = 0; mi < 4; ++mi)
#pragma unroll
            for (int ni = 0; ni < 4; ++ni)
                acc[mi][ni] = __builtin_amdgcn_mfma_f32_16x16x32_bf16(
                    af[mi], bfr[ni], acc[mi][ni], 0, 0, 0);

        __syncthreads();                     // joins: reads of cur done, next buffer landed
    }

    // epilogue: C/D layout col = lane&15 (n=p), row = quad*4 + reg (m=co)
    const int pcol = Nb * 128 + wn * 64 + ln15;
    const int corow = Mb * 128 + wm * 64 + quad * 4;
#pragma unroll
    for (int mi = 0; mi < 4; ++mi)
#pragma unroll
        for (int ni = 0; ni < 4; ++ni)
#pragma unroll
            for (int r = 0; r < 4; ++r)
                out[(corow + mi * 16 + r) * NPOS + pcol + ni * 16] = acc[mi][ni][r];
}

extern "C" void kernel_launch(void* const* d_in, const int* in_sizes, int n_in,
                              void* d_out, int out_size, void* d_ws, size_t ws_size,
                              hipStream_t stream) {
    const float* x = (const float*)d_in[0];       // [1,256,224,224]
    const float* w = (const float*)d_in[1];       // [256,256,3,3]
    float* out = (float*)d_out;                   // [256,224,224]

    unsigned short* xp = (unsigned short*)d_ws;        // 13,075,456 shorts
    unsigned short* ap = xp + XP_ELEMS;                // 589,824 shorts

    prep_kernel<<<XT_BLOCKS + WT_BLOCKS + 113, 256, 0, stream>>>(x, w, ap, xp);
    gemm_conv_kernel<<<dim3(NPOS / 128, CO / 128), 256, 0, stream>>>(ap, xp, out);
}